// Round 10
// baseline (547.267 us; speedup 1.0000x reference)
//
#include <hip/hip_runtime.h>
#include <stdint.h>

#define N_NODES 50000
#define N_EDGES 400000
#define MPAD    50048   // 391 * 128
#define G_GEMM  1564    // (MPAD/128)*4 gemm blocks in fused layer-0 launch
#define H_BLKS  1563    // (N_EDGES+255)/256 hist blocks appended after them

typedef __bf16 bf16x8 __attribute__((ext_vector_type(8)));
typedef float  f32x4  __attribute__((ext_vector_type(4)));
typedef unsigned short ushort_t;
typedef unsigned int   uint_t;

// ---------- bf16 helpers (RNE) ----------
__device__ __forceinline__ ushort_t f2b(float f){
    uint_t x = __float_as_uint(f);
    x += 0x7FFFu + ((x >> 16) & 1u);
    return (ushort_t)(x >> 16);
}
__device__ __forceinline__ float b2f(ushort_t h){
    return __uint_as_float(((uint_t)h) << 16);
}

// ---------- bijective XCD-chunked swizzle (m204) ----------
// bn-fastest logical order + contiguous logical chunk per XCD: round-3
// verified (A FETCH 203 MB -> 54 MB on gemm128_a32).
__device__ __forceinline__ int xcd_swz(int orig, int nwg){
    int q = nwg >> 3, r = nwg & 7;
    int xcd = orig & 7, idx = orig >> 3;
    int base = (xcd < r) ? xcd * (q + 1) : r * (q + 1) + (xcd - r) * q;
    return base + idx;
}

// ---------- L1: fused weight transpose + deg/cursor zero ----------
// blocks 0..639: W transposes (W0 256, W1 256, W2 128). blocks 640..835: zero.
__global__ __launch_bounds__(256) void pre_kernel(
        const float* __restrict__ W0, const float* __restrict__ W1,
        const float* __restrict__ W2, ushort_t* __restrict__ W0t,
        ushort_t* __restrict__ W1t, ushort_t* __restrict__ W2t,
        int* __restrict__ deg, int* __restrict__ cursor){
    int b = blockIdx.x;
    if (b >= 640){
        int i = (b - 640) * 256 + threadIdx.x;
        if (i < N_NODES){ deg[i] = 0; cursor[i] = 0; }
        return;
    }
    __shared__ float t[32][33];
    const float* W; ushort_t* Wt; int K, N, bx, by;
    if (b < 256){            W = W0; Wt = W0t; K = 512; N = 512;
                             bx = (b & 15) * 32; by = (b >> 4) * 32; }
    else if (b < 512){ b -= 256; W = W1; Wt = W1t; K = 512; N = 512;
                             bx = (b & 15) * 32; by = (b >> 4) * 32; }
    else {             b -= 512; W = W2; Wt = W2t; K = 512; N = 256;
                             bx = (b & 7) * 32;  by = (b >> 3) * 32; }
    const int x = threadIdx.x & 31, y = threadIdx.x >> 5;   // 32 x 8
    #pragma unroll
    for (int j = 0; j < 32; j += 8)
        t[y + j][x] = W[(size_t)(by + y + j) * N + bx + x];
    __syncthreads();
    #pragma unroll
    for (int j = 0; j < 32; j += 8)
        Wt[(size_t)(bx + y + j) * K + by + x] = f2b(t[x][y + j]);
}

// ---------- L3: single-block exclusive scan of deg -> offs ----------
// 1024 threads x 49 elems (50176 >= 50000). deg is L2-hot from hist.
__global__ __launch_bounds__(1024) void scan50k(const int* __restrict__ deg,
                                                int* __restrict__ offs){
    __shared__ int sums[1024];
    const int t = threadIdx.x;
    const int base = t * 49;
    int s = 0;
    #pragma unroll
    for (int j = 0; j < 49; j++){
        int i = base + j;
        s += (i < N_NODES) ? deg[i] : 0;
    }
    sums[t] = s; __syncthreads();
    for (int off = 1; off < 1024; off <<= 1){
        int x = (t >= off) ? sums[t - off] : 0;
        __syncthreads();
        sums[t] += x;
        __syncthreads();
    }
    int excl = sums[t] - s;           // exclusive prefix of this thread's chunk
    #pragma unroll
    for (int j = 0; j < 49; j++){
        int i = base + j;
        if (i < N_NODES){
            int v = deg[i];
            offs[i] = excl;
            excl += v;
        }
    }
    if (t == 0) offs[N_NODES] = N_EDGES;
}

// ---------- L4: CSR fill ----------
__global__ void fill_kernel(const int* __restrict__ src, const int* __restrict__ dst,
                            const int* __restrict__ offs, int* __restrict__ cursor,
                            int* __restrict__ nbr, int E){
    int i = blockIdx.x * blockDim.x + threadIdx.x;
    if (i < E){
        int d = dst[i];
        int p = atomicAdd(&cursor[d], 1);
        nbr[offs[d] + p] = src[i];
    }
}

// ---------- GEMM helpers ----------
__device__ __forceinline__ void load16(const void* g, void* l){
    __builtin_amdgcn_global_load_lds((const __attribute__((address_space(1))) void*)g,
                                     (__attribute__((address_space(3))) void*)l, 16, 0, 0);
}

// ---------- GEMM: 128x128 tile, BK=64, 4 waves (2x2 of 64x64) ----------
// Round-7/9 verified: 71.4 us layer-0, FETCH 54 MB, 0 bank conflicts, VGPR 64
// (no spill). NOTE: acc[4][4] f32x4 = 64 VGPR -> never request >4 waves/EU
// (round-8 lesson: (512,6) capped VGPR at 40 -> 627 MB scratch spill, 4.5x slower).
__global__ __launch_bounds__(256, 4) void gemm128_bt(const ushort_t* __restrict__ A,
                                                     const ushort_t* __restrict__ Bt,
                                                     ushort_t* __restrict__ C,
                                                     int NBN, int N, int K){
    __shared__ ushort_t As[128 * 64];   // 16 KB
    __shared__ ushort_t Bs[128 * 64];   // 16 KB
    const int tid  = threadIdx.x, lane = tid & 63, wave = tid >> 6;
    const int wg = xcd_swz(blockIdx.x, gridDim.x);
    const int bm = wg / NBN, bn = wg - bm * NBN;
    const int fr = lane & 15;
    const int wm = (wave >> 1) * 64, wn = (wave & 1) * 64;
    f32x4 acc[4][4] = {};

    for (int kt = 0; kt < K; kt += 64){
        __syncthreads();
        #pragma unroll
        for (int i = 0; i < 4; i++){    // A: 1024 chunks of 16B
            int s = tid + i * 256;
            int row = s >> 3, p = s & 7, c = p ^ (row & 7);
            load16(A + (size_t)(bm * 128 + row) * K + kt + c * 8,
                   (char*)As + s * 16);
        }
        #pragma unroll
        for (int i = 0; i < 4; i++){    // B: 1024 chunks
            int s = tid + i * 256;
            int row = s >> 3, p = s & 7, c = p ^ (row & 7);
            load16(Bt + (size_t)(bn * 128 + row) * K + kt + c * 8,
                   (char*)Bs + s * 16);
        }
        __syncthreads();   // vmcnt(0): staging complete
        #pragma unroll
        for (int ks = 0; ks < 2; ks++){
            const int c = (lane >> 4) + ks * 4;
            const int cx = c ^ (fr & 7);
            bf16x8 af[4], bf[4];
            #pragma unroll
            for (int t = 0; t < 4; t++)
                af[t] = *(const bf16x8*)(const void*)(As + (wm + t * 16 + fr) * 64 + cx * 8);
            #pragma unroll
            for (int t = 0; t < 4; t++)
                bf[t] = *(const bf16x8*)(const void*)(Bs + (wn + t * 16 + fr) * 64 + cx * 8);
            #pragma unroll
            for (int tm = 0; tm < 4; tm++)
                #pragma unroll
                for (int tn = 0; tn < 4; tn++)
                    acc[tm][tn] = __builtin_amdgcn_mfma_f32_16x16x32_bf16(
                                      af[tm], bf[tn], acc[tm][tn], 0, 0, 0);
        }
    }
    // epilogue: C/D layout col=lane&15, row=(lane>>4)*4+reg  [m89-verified]
    const int r0 = (lane >> 4) * 4, c0 = lane & 15;
    #pragma unroll
    for (int tm = 0; tm < 4; tm++){
        #pragma unroll
        for (int tn = 0; tn < 4; tn++){
            int rbase = bm * 128 + wm + tm * 16 + r0;
            int cidx  = bn * 128 + wn + tn * 16 + c0;
            #pragma unroll
            for (int reg = 0; reg < 4; reg++)
                C[(size_t)(rbase + reg) * N + cidx] = f2b(acc[tm][tn][reg]);
        }
    }
}

// ---------- L2: layer-0 GEMM (fp32 A, fused f2b) + fused hist ----------
// Blocks [0, G_GEMM): GEMM (identical body to round-9 gemm128_a32).
// Blocks [G_GEMM, G_GEMM+H_BLKS): degree histogram (independent work; placed
// AFTER the gemm blocks so the leading 1564 blocks keep the same blockIdx%8
// -> XCD mapping the swizzle was verified with). Whole-block early return:
// no barrier divergence.
__global__ __launch_bounds__(256, 4) void gemm128_a32h(const float* __restrict__ A,
                                                       const ushort_t* __restrict__ Bt,
                                                       ushort_t* __restrict__ C,
                                                       const int* __restrict__ dst,
                                                       int* __restrict__ deg,
                                                       int K){
    __shared__ ushort_t As[128 * 64];
    __shared__ ushort_t Bs[128 * 64];
    if (blockIdx.x >= G_GEMM){
        int i = (blockIdx.x - G_GEMM) * 256 + threadIdx.x;
        if (i < N_EDGES) atomicAdd(&deg[dst[i]], 1);
        return;
    }
    const int tid  = threadIdx.x, lane = tid & 63, wave = tid >> 6;
    const int wg = xcd_swz(blockIdx.x, G_GEMM);
    const int bm = wg >> 2, bn = wg & 3;          // NBN = 4 (N = 512)
    const int fr = lane & 15;
    const int wm = (wave >> 1) * 64, wn = (wave & 1) * 64;
    f32x4 acc[4][4] = {};

    for (int kt = 0; kt < K; kt += 64){
        __syncthreads();
        // A: issue fp32 loads first (reg round-trip), then B async, then convert.
        float4 x[4], y[4];
        #pragma unroll
        for (int i = 0; i < 4; i++){
            int s = tid + i * 256;
            int row = s >> 3, p = s & 7, c = p ^ (row & 7);
            int grow = bm * 128 + row;
            if (grow < N_NODES){
                const float* pp = A + (size_t)grow * K + kt + c * 8;
                x[i] = *(const float4*)(const void*)pp;
                y[i] = *(const float4*)(const void*)(pp + 4);
            } else {
                x[i] = make_float4(0.f, 0.f, 0.f, 0.f);
                y[i] = make_float4(0.f, 0.f, 0.f, 0.f);
            }
        }
        #pragma unroll
        for (int i = 0; i < 4; i++){    // B: async direct-to-LDS
            int s = tid + i * 256;
            int row = s >> 3, p = s & 7, c = p ^ (row & 7);
            load16(Bt + (size_t)(bn * 128 + row) * K + kt + c * 8,
                   (char*)Bs + s * 16);
        }
        #pragma unroll
        for (int i = 0; i < 4; i++){    // convert + linear ds_write_b128
            int s = tid + i * 256;
            uint4 o;
            o.x = (uint_t)f2b(x[i].x) | ((uint_t)f2b(x[i].y) << 16);
            o.y = (uint_t)f2b(x[i].z) | ((uint_t)f2b(x[i].w) << 16);
            o.z = (uint_t)f2b(y[i].x) | ((uint_t)f2b(y[i].y) << 16);
            o.w = (uint_t)f2b(y[i].z) | ((uint_t)f2b(y[i].w) << 16);
            *(uint4*)(void*)((char*)As + s * 16) = o;
        }
        __syncthreads();
        #pragma unroll
        for (int ks = 0; ks < 2; ks++){
            const int c = (lane >> 4) + ks * 4;
            const int cx = c ^ (fr & 7);
            bf16x8 af[4], bf[4];
            #pragma unroll
            for (int t = 0; t < 4; t++)
                af[t] = *(const bf16x8*)(const void*)(As + (wm + t * 16 + fr) * 64 + cx * 8);
            #pragma unroll
            for (int t = 0; t < 4; t++)
                bf[t] = *(const bf16x8*)(const void*)(Bs + (wn + t * 16 + fr) * 64 + cx * 8);
            #pragma unroll
            for (int tm = 0; tm < 4; tm++)
                #pragma unroll
                for (int tn = 0; tn < 4; tn++)
                    acc[tm][tn] = __builtin_amdgcn_mfma_f32_16x16x32_bf16(
                                      af[tm], bf[tn], acc[tm][tn], 0, 0, 0);
        }
    }
    const int r0 = (lane >> 4) * 4, c0 = lane & 15;
    #pragma unroll
    for (int tm = 0; tm < 4; tm++){
        #pragma unroll
        for (int tn = 0; tn < 4; tn++){
            int rbase = bm * 128 + wm + tm * 16 + r0;
            int cidx  = bn * 128 + wn + tn * 16 + c0;
            #pragma unroll
            for (int reg = 0; reg < 4; reg++)
                C[(size_t)(rbase + reg) * 512 + cidx] = f2b(acc[tm][tn][reg]);
        }
    }
}

// ---------- aggregation ----------
__device__ __forceinline__ void acc8(float* a, uint4 y){
    a[0] += b2f((ushort_t)(y.x & 0xffff)); a[1] += b2f((ushort_t)(y.x >> 16));
    a[2] += b2f((ushort_t)(y.y & 0xffff)); a[3] += b2f((ushort_t)(y.y >> 16));
    a[4] += b2f((ushort_t)(y.z & 0xffff)); a[5] += b2f((ushort_t)(y.z >> 16));
    a[6] += b2f((ushort_t)(y.w & 0xffff)); a[7] += b2f((ushort_t)(y.w >> 16));
}
__device__ __forceinline__ void acc4(float* a, uint2 y){
    a[0] += b2f((ushort_t)(y.x & 0xffff)); a[1] += b2f((ushort_t)(y.x >> 16));
    a[2] += b2f((ushort_t)(y.y & 0xffff)); a[3] += b2f((ushort_t)(y.y >> 16));
}

// H[v] = relu((sum Y[nbr] + Y[v]) / (deg+1) + b), d=512, bf16 out.
// Dual-node waves (round-9, neutral-vs-best), 16B/lane loads preserved.
__global__ __launch_bounds__(256) void agg_relu_kernel(
        const ushort_t* __restrict__ Y, const int* __restrict__ offs,
        const int* __restrict__ nbr, const float* __restrict__ bias,
        ushort_t* __restrict__ H){
    const int lane = threadIdx.x & 63, wave = threadIdx.x >> 6;
    const int v0 = blockIdx.x * 8 + wave * 2, v1 = v0 + 1;
    const int off = lane * 8;
    float a0[8], a1[8];
    {   uint4 y = *(const uint4*)(const void*)(Y + (size_t)v0 * 512 + off);
        a0[0] = b2f((ushort_t)(y.x & 0xffff)); a0[1] = b2f((ushort_t)(y.x >> 16));
        a0[2] = b2f((ushort_t)(y.y & 0xffff)); a0[3] = b2f((ushort_t)(y.y >> 16));
        a0[4] = b2f((ushort_t)(y.z & 0xffff)); a0[5] = b2f((ushort_t)(y.z >> 16));
        a0[6] = b2f((ushort_t)(y.w & 0xffff)); a0[7] = b2f((ushort_t)(y.w >> 16)); }
    {   uint4 y = *(const uint4*)(const void*)(Y + (size_t)v1 * 512 + off);
        a1[0] = b2f((ushort_t)(y.x & 0xffff)); a1[1] = b2f((ushort_t)(y.x >> 16));
        a1[2] = b2f((ushort_t)(y.y & 0xffff)); a1[3] = b2f((ushort_t)(y.y >> 16));
        a1[4] = b2f((ushort_t)(y.z & 0xffff)); a1[5] = b2f((ushort_t)(y.z >> 16));
        a1[6] = b2f((ushort_t)(y.w & 0xffff)); a1[7] = b2f((ushort_t)(y.w >> 16)); }
    const int beg0 = offs[v0], end0 = offs[v0 + 1];
    const int beg1 = offs[v1], end1 = offs[v1 + 1];
    int i0 = beg0, i1 = beg1;
    while (i0 + 4 <= end0 && i1 + 4 <= end1){
        uint4 yy0[4], yy1[4];
        #pragma unroll
        for (int j = 0; j < 4; j++){
            int u = nbr[i0 + j];
            yy0[j] = *(const uint4*)(const void*)(Y + (size_t)u * 512 + off);
        }
        #pragma unroll
        for (int j = 0; j < 4; j++){
            int u = nbr[i1 + j];
            yy1[j] = *(const uint4*)(const void*)(Y + (size_t)u * 512 + off);
        }
        #pragma unroll
        for (int j = 0; j < 4; j++) acc8(a0, yy0[j]);
        #pragma unroll
        for (int j = 0; j < 4; j++) acc8(a1, yy1[j]);
        i0 += 4; i1 += 4;
    }
    for (; i0 + 4 <= end0; i0 += 4){
        uint4 yy[4];
        #pragma unroll
        for (int j = 0; j < 4; j++){
            int u = nbr[i0 + j];
            yy[j] = *(const uint4*)(const void*)(Y + (size_t)u * 512 + off);
        }
        #pragma unroll
        for (int j = 0; j < 4; j++) acc8(a0, yy[j]);
    }
    for (; i0 < end0; i0++){
        int u = nbr[i0];
        uint4 y = *(const uint4*)(const void*)(Y + (size_t)u * 512 + off);
        acc8(a0, y);
    }
    for (; i1 + 4 <= end1; i1 += 4){
        uint4 yy[4];
        #pragma unroll
        for (int j = 0; j < 4; j++){
            int u = nbr[i1 + j];
            yy[j] = *(const uint4*)(const void*)(Y + (size_t)u * 512 + off);
        }
        #pragma unroll
        for (int j = 0; j < 4; j++) acc8(a1, yy[j]);
    }
    for (; i1 < end1; i1++){
        int u = nbr[i1];
        uint4 y = *(const uint4*)(const void*)(Y + (size_t)u * 512 + off);
        acc8(a1, y);
    }
    float4 bb0 = ((const float4*)bias)[lane * 2];
    float4 bb1 = ((const float4*)bias)[lane * 2 + 1];
    {
        const float inv = 1.0f / (float)(end0 - beg0 + 1);
        float r[8];
        r[0] = a0[0]*inv + bb0.x; r[1] = a0[1]*inv + bb0.y;
        r[2] = a0[2]*inv + bb0.z; r[3] = a0[3]*inv + bb0.w;
        r[4] = a0[4]*inv + bb1.x; r[5] = a0[5]*inv + bb1.y;
        r[6] = a0[6]*inv + bb1.z; r[7] = a0[7]*inv + bb1.w;
        #pragma unroll
        for (int j = 0; j < 8; j++) r[j] = r[j] > 0.f ? r[j] : 0.f;
        uint4 o;
        o.x = (uint_t)f2b(r[0]) | ((uint_t)f2b(r[1]) << 16);
        o.y = (uint_t)f2b(r[2]) | ((uint_t)f2b(r[3]) << 16);
        o.z = (uint_t)f2b(r[4]) | ((uint_t)f2b(r[5]) << 16);
        o.w = (uint_t)f2b(r[6]) | ((uint_t)f2b(r[7]) << 16);
        *(uint4*)(void*)(H + (size_t)v0 * 512 + off) = o;
    }
    {
        const float inv = 1.0f / (float)(end1 - beg1 + 1);
        float r[8];
        r[0] = a1[0]*inv + bb0.x; r[1] = a1[1]*inv + bb0.y;
        r[2] = a1[2]*inv + bb0.z; r[3] = a1[3]*inv + bb0.w;
        r[4] = a1[4]*inv + bb1.x; r[5] = a1[5]*inv + bb1.y;
        r[6] = a1[6]*inv + bb1.z; r[7] = a1[7]*inv + bb1.w;
        #pragma unroll
        for (int j = 0; j < 8; j++) r[j] = r[j] > 0.f ? r[j] : 0.f;
        uint4 o;
        o.x = (uint_t)f2b(r[0]) | ((uint_t)f2b(r[1]) << 16);
        o.y = (uint_t)f2b(r[2]) | ((uint_t)f2b(r[3]) << 16);
        o.z = (uint_t)f2b(r[4]) | ((uint_t)f2b(r[5]) << 16);
        o.w = (uint_t)f2b(r[6]) | ((uint_t)f2b(r[7]) << 16);
        *(uint4*)(void*)(H + (size_t)v1 * 512 + off) = o;
    }
}

// final layer: d=256, fp32 out, no relu. wave per node, lane covers 4 elems
__global__ __launch_bounds__(256) void agg_out_kernel(
        const ushort_t* __restrict__ Y, const int* __restrict__ offs,
        const int* __restrict__ nbr, const float* __restrict__ bias,
        float* __restrict__ out){
    const int lane = threadIdx.x & 63, wave = threadIdx.x >> 6;
    const int v = blockIdx.x * 4 + wave;
    const int off = lane * 4;
    float a[4];
    {   uint2 y = *(const uint2*)(const void*)(Y + (size_t)v * 256 + off);
        a[0] = b2f((ushort_t)(y.x & 0xffff)); a[1] = b2f((ushort_t)(y.x >> 16));
        a[2] = b2f((ushort_t)(y.y & 0xffff)); a[3] = b2f((ushort_t)(y.y >> 16)); }
    const int beg = offs[v], end = offs[v + 1];
    int i = beg;
    for (; i + 8 <= end; i += 8){
        uint2 yy[8];
        #pragma unroll
        for (int j = 0; j < 8; j++){
            int u = nbr[i + j];
            yy[j] = *(const uint2*)(const void*)(Y + (size_t)u * 256 + off);
        }
        #pragma unroll
        for (int j = 0; j < 8; j++) acc4(a, yy[j]);
    }
    for (; i + 4 <= end; i += 4){
        uint2 yy[4];
        #pragma unroll
        for (int j = 0; j < 4; j++){
            int u = nbr[i + j];
            yy[j] = *(const uint2*)(const void*)(Y + (size_t)u * 256 + off);
        }
        #pragma unroll
        for (int j = 0; j < 4; j++) acc4(a, yy[j]);
    }
    for (; i < end; i++){
        int u = nbr[i];
        uint2 y = *(const uint2*)(const void*)(Y + (size_t)u * 256 + off);
        acc4(a, y);
    }
    const float inv = 1.0f / (float)(end - beg + 1);
    float4 bb = ((const float4*)bias)[lane];
    float4 r;
    r.x = a[0]*inv + bb.x; r.y = a[1]*inv + bb.y;
    r.z = a[2]*inv + bb.z; r.w = a[3]*inv + bb.w;
    ((float4*)out)[v * 64 + lane] = r;
}

extern "C" void kernel_launch(void* const* d_in, const int* in_sizes, int n_in,
                              void* d_out, int out_size, void* d_ws, size_t ws_size,
                              hipStream_t stream) {
    const float* feats = (const float*)d_in[0];
    const int*   src   = (const int*)  d_in[1];
    const int*   dst   = (const int*)  d_in[2];
    const float* W0    = (const float*)d_in[3];
    const float* b0    = (const float*)d_in[4];
    const float* W1    = (const float*)d_in[5];
    const float* b1    = (const float*)d_in[6];
    const float* W2    = (const float*)d_in[7];
    const float* b2    = (const float*)d_in[8];
    float* out = (float*)d_out;

    char* w = (char*)d_ws;
    ushort_t* Abuf = (ushort_t*)w;  w += (size_t)MPAD * 512 * 2;   // 51.25 MB (H buffer)
    ushort_t* Ybuf = (ushort_t*)w;  w += (size_t)MPAD * 512 * 2;   // 51.25 MB
    ushort_t* W0t  = (ushort_t*)w;  w += 512 * 512 * 2;
    ushort_t* W1t  = (ushort_t*)w;  w += 512 * 512 * 2;
    ushort_t* W2t  = (ushort_t*)w;  w += 256 * 512 * 2;
    int* deg    = (int*)w;          w += 50048 * 4;
    int* offs   = (int*)w;          w += 50056 * 4;
    int* cursor = (int*)w;          w += 50048 * 4;
    int* nbr    = (int*)w;          w += (size_t)N_EDGES * 4;
    int* bsum   = (int*)w;          w += 64 * 4;

    // L1: weight transposes + deg/cursor zero (fused, independent outputs)
    pre_kernel<<<836, 256, 0, stream>>>(W0, W1, W2, W0t, W1t, W2t, deg, cursor);
    // L2: layer-0 GEMM (needs only W0t) + degree histogram (needs only zeroed deg)
    gemm128_a32h<<<G_GEMM + H_BLKS, 256, 0, stream>>>(feats, W0t, Ybuf, dst, deg, 512);
    // L3: single-block scan deg -> offs
    scan50k<<<1, 1024, 0, stream>>>(deg, offs);
    // L4: CSR fill
    fill_kernel<<<H_BLKS, 256, 0, stream>>>(src, dst, offs, cursor, nbr, N_EDGES);
    // L5: layer-0 aggregation
    agg_relu_kernel<<<N_NODES / 8, 256, 0, stream>>>(Ybuf, offs, nbr, b0, Abuf);
    // L6/L7: layer 1
    gemm128_bt<<<(MPAD / 128) * 4, 256, 0, stream>>>(Abuf, W1t, Ybuf, 4, 512, 512);
    agg_relu_kernel<<<N_NODES / 8, 256, 0, stream>>>(Ybuf, offs, nbr, b1, Abuf);
    // L8/L9: layer 2 (no relu, fp32 out)
    gemm128_bt<<<(MPAD / 128) * 2, 256, 0, stream>>>(Abuf, W2t, Ybuf, 2, 256, 512);
    agg_out_kernel<<<N_NODES / 4, 256, 0, stream>>>(Ybuf, offs, nbr, b2, out);
}

// Round 11
// 466.176 us; speedup vs baseline: 1.1739x; 1.1739x over previous
//
#include <hip/hip_runtime.h>
#include <stdint.h>

#define N_NODES 50000
#define N_EDGES 400000
#define MPAD    50048   // 391 * 128
#define SCAN_B  49      // ceil(50000/1024)
#define G_GEMM  1564    // (MPAD/128)*4 gemm blocks in fused layer-0 launch
#define H_BLKS  1563    // (N_EDGES+255)/256 hist blocks appended after them

typedef __bf16 bf16x8 __attribute__((ext_vector_type(8)));
typedef float  f32x4  __attribute__((ext_vector_type(4)));
typedef unsigned short ushort_t;
typedef unsigned int   uint_t;

// ---------- bf16 helpers (RNE) ----------
__device__ __forceinline__ ushort_t f2b(float f){
    uint_t x = __float_as_uint(f);
    x += 0x7FFFu + ((x >> 16) & 1u);
    return (ushort_t)(x >> 16);
}
__device__ __forceinline__ float b2f(ushort_t h){
    return __uint_as_float(((uint_t)h) << 16);
}

// ---------- bijective XCD-chunked swizzle (m204) ----------
// bn-fastest logical order + contiguous logical chunk per XCD: round-3
// verified (A FETCH 203 MB -> 54 MB on gemm128_a32).
__device__ __forceinline__ int xcd_swz(int orig, int nwg){
    int q = nwg >> 3, r = nwg & 7;
    int xcd = orig & 7, idx = orig >> 3;
    int base = (xcd < r) ? xcd * (q + 1) : r * (q + 1) + (xcd - r) * q;
    return base + idx;
}

// ---------- L1: fused weight transpose + deg/cursor zero ----------
// blocks 0..639: W transposes (W0 256, W1 256, W2 128). blocks 640..835: zero.
// (round-10: measured harmless)
__global__ __launch_bounds__(256) void pre_kernel(
        const float* __restrict__ W0, const float* __restrict__ W1,
        const float* __restrict__ W2, ushort_t* __restrict__ W0t,
        ushort_t* __restrict__ W1t, ushort_t* __restrict__ W2t,
        int* __restrict__ deg, int* __restrict__ cursor){
    int b = blockIdx.x;
    if (b >= 640){
        int i = (b - 640) * 256 + threadIdx.x;
        if (i < N_NODES){ deg[i] = 0; cursor[i] = 0; }
        return;
    }
    __shared__ float t[32][33];
    const float* W; ushort_t* Wt; int K, N, bx, by;
    if (b < 256){            W = W0; Wt = W0t; K = 512; N = 512;
                             bx = (b & 15) * 32; by = (b >> 4) * 32; }
    else if (b < 512){ b -= 256; W = W1; Wt = W1t; K = 512; N = 512;
                             bx = (b & 15) * 32; by = (b >> 4) * 32; }
    else {             b -= 512; W = W2; Wt = W2t; K = 512; N = 256;
                             bx = (b & 7) * 32;  by = (b >> 3) * 32; }
    const int x = threadIdx.x & 31, y = threadIdx.x >> 5;   // 32 x 8
    #pragma unroll
    for (int j = 0; j < 32; j += 8)
        t[y + j][x] = W[(size_t)(by + y + j) * N + bx + x];
    __syncthreads();
    #pragma unroll
    for (int j = 0; j < 32; j += 8)
        Wt[(size_t)(bx + y + j) * K + by + x] = f2b(t[x][y + j]);
}

// ---------- L3: per-block scan (round-9 proven form; 49 blocks) ----------
// round-10 lesson: a single-block 50k scan = 87 us (1 CU, stride-49 reads).
// Multi-block + tiny redundant top-level scan is ~25x cheaper.
__global__ __launch_bounds__(1024) void blk_scan_kernel(
        const int* __restrict__ deg, int* __restrict__ offs,
        int* __restrict__ bsum, int n){
    __shared__ int buf[1024];
    const int t = threadIdx.x, b = blockIdx.x;
    const int i = b * 1024 + t;
    int v = (i < n) ? deg[i] : 0;
    buf[t] = v; __syncthreads();
    for (int off = 1; off < 1024; off <<= 1){
        int x = (t >= off) ? buf[t - off] : 0;
        __syncthreads();
        buf[t] += x;
        __syncthreads();
    }
    if (i < n) offs[i] = buf[t] - v;          // local exclusive prefix
    if (t == 1023) bsum[b] = buf[1023];       // block total
}

// ---------- L4: add block offsets; bsum scanned REDUNDANTLY per block ----------
// wave 0 of every block shuffle-scans the 49 block totals (L2-hot, ~49 ints)
// -> removes the separate bsum_scan launch.
__global__ __launch_bounds__(1024) void add_off2_kernel(
        int* __restrict__ offs, const int* __restrict__ bsum, int n){
    __shared__ int boff;
    if (threadIdx.x < 64){
        int t = threadIdx.x;
        int own = (t < SCAN_B) ? bsum[t] : 0;
        int v = own;
        #pragma unroll
        for (int off = 1; off < 64; off <<= 1){
            int x = __shfl_up(v, off, 64);
            if (t >= off) v += x;
        }
        if (t == blockIdx.x) boff = v - own;  // exclusive prefix at this block
    }
    __syncthreads();
    int i = blockIdx.x * 1024 + threadIdx.x;
    if (i < n) offs[i] += boff;
    if (i == 0) offs[n] = N_EDGES;
}

// ---------- L5: CSR fill ----------
__global__ void fill_kernel(const int* __restrict__ src, const int* __restrict__ dst,
                            const int* __restrict__ offs, int* __restrict__ cursor,
                            int* __restrict__ nbr, int E){
    int i = blockIdx.x * blockDim.x + threadIdx.x;
    if (i < E){
        int d = dst[i];
        int p = atomicAdd(&cursor[d], 1);
        nbr[offs[d] + p] = src[i];
    }
}

// ---------- GEMM helpers ----------
__device__ __forceinline__ void load16(const void* g, void* l){
    __builtin_amdgcn_global_load_lds((const __attribute__((address_space(1))) void*)g,
                                     (__attribute__((address_space(3))) void*)l, 16, 0, 0);
}

// ---------- GEMM: 128x128 tile, BK=64, 4 waves (2x2 of 64x64) ----------
// Round-7/9 verified: 71.4 us layer-0, FETCH 54 MB, 0 bank conflicts, VGPR 64
// (no spill). NOTE: acc[4][4] f32x4 = 64 VGPR -> never request >4 waves/EU
// (round-8 lesson: (512,6) capped VGPR at 40 -> 627 MB scratch spill, 4.5x slower).
__global__ __launch_bounds__(256, 4) void gemm128_bt(const ushort_t* __restrict__ A,
                                                     const ushort_t* __restrict__ Bt,
                                                     ushort_t* __restrict__ C,
                                                     int NBN, int N, int K){
    __shared__ ushort_t As[128 * 64];   // 16 KB
    __shared__ ushort_t Bs[128 * 64];   // 16 KB
    const int tid  = threadIdx.x, lane = tid & 63, wave = tid >> 6;
    const int wg = xcd_swz(blockIdx.x, gridDim.x);
    const int bm = wg / NBN, bn = wg - bm * NBN;
    const int fr = lane & 15;
    const int wm = (wave >> 1) * 64, wn = (wave & 1) * 64;
    f32x4 acc[4][4] = {};

    for (int kt = 0; kt < K; kt += 64){
        __syncthreads();
        #pragma unroll
        for (int i = 0; i < 4; i++){    // A: 1024 chunks of 16B
            int s = tid + i * 256;
            int row = s >> 3, p = s & 7, c = p ^ (row & 7);
            load16(A + (size_t)(bm * 128 + row) * K + kt + c * 8,
                   (char*)As + s * 16);
        }
        #pragma unroll
        for (int i = 0; i < 4; i++){    // B: 1024 chunks
            int s = tid + i * 256;
            int row = s >> 3, p = s & 7, c = p ^ (row & 7);
            load16(Bt + (size_t)(bn * 128 + row) * K + kt + c * 8,
                   (char*)Bs + s * 16);
        }
        __syncthreads();   // vmcnt(0): staging complete
        #pragma unroll
        for (int ks = 0; ks < 2; ks++){
            const int c = (lane >> 4) + ks * 4;
            const int cx = c ^ (fr & 7);
            bf16x8 af[4], bf[4];
            #pragma unroll
            for (int t = 0; t < 4; t++)
                af[t] = *(const bf16x8*)(const void*)(As + (wm + t * 16 + fr) * 64 + cx * 8);
            #pragma unroll
            for (int t = 0; t < 4; t++)
                bf[t] = *(const bf16x8*)(const void*)(Bs + (wn + t * 16 + fr) * 64 + cx * 8);
            #pragma unroll
            for (int tm = 0; tm < 4; tm++)
                #pragma unroll
                for (int tn = 0; tn < 4; tn++)
                    acc[tm][tn] = __builtin_amdgcn_mfma_f32_16x16x32_bf16(
                                      af[tm], bf[tn], acc[tm][tn], 0, 0, 0);
        }
    }
    // epilogue: C/D layout col=lane&15, row=(lane>>4)*4+reg  [m89-verified]
    const int r0 = (lane >> 4) * 4, c0 = lane & 15;
    #pragma unroll
    for (int tm = 0; tm < 4; tm++){
        #pragma unroll
        for (int tn = 0; tn < 4; tn++){
            int rbase = bm * 128 + wm + tm * 16 + r0;
            int cidx  = bn * 128 + wn + tn * 16 + c0;
            #pragma unroll
            for (int reg = 0; reg < 4; reg++)
                C[(size_t)(rbase + reg) * N + cidx] = f2b(acc[tm][tn][reg]);
        }
    }
}

// ---------- L2: layer-0 GEMM (fp32 A, fused f2b) + fused hist ----------
// Blocks [0, G_GEMM): GEMM. Blocks [G_GEMM, +H_BLKS): degree histogram.
// (round-10: measured harmless; whole-block early return, no barrier divergence)
__global__ __launch_bounds__(256, 4) void gemm128_a32h(const float* __restrict__ A,
                                                       const ushort_t* __restrict__ Bt,
                                                       ushort_t* __restrict__ C,
                                                       const int* __restrict__ dst,
                                                       int* __restrict__ deg,
                                                       int K){
    __shared__ ushort_t As[128 * 64];
    __shared__ ushort_t Bs[128 * 64];
    if (blockIdx.x >= G_GEMM){
        int i = (blockIdx.x - G_GEMM) * 256 + threadIdx.x;
        if (i < N_EDGES) atomicAdd(&deg[dst[i]], 1);
        return;
    }
    const int tid  = threadIdx.x, lane = tid & 63, wave = tid >> 6;
    const int wg = xcd_swz(blockIdx.x, G_GEMM);
    const int bm = wg >> 2, bn = wg & 3;          // NBN = 4 (N = 512)
    const int fr = lane & 15;
    const int wm = (wave >> 1) * 64, wn = (wave & 1) * 64;
    f32x4 acc[4][4] = {};

    for (int kt = 0; kt < K; kt += 64){
        __syncthreads();
        // A: issue fp32 loads first (reg round-trip), then B async, then convert.
        float4 x[4], y[4];
        #pragma unroll
        for (int i = 0; i < 4; i++){
            int s = tid + i * 256;
            int row = s >> 3, p = s & 7, c = p ^ (row & 7);
            int grow = bm * 128 + row;
            if (grow < N_NODES){
                const float* pp = A + (size_t)grow * K + kt + c * 8;
                x[i] = *(const float4*)(const void*)pp;
                y[i] = *(const float4*)(const void*)(pp + 4);
            } else {
                x[i] = make_float4(0.f, 0.f, 0.f, 0.f);
                y[i] = make_float4(0.f, 0.f, 0.f, 0.f);
            }
        }
        #pragma unroll
        for (int i = 0; i < 4; i++){    // B: async direct-to-LDS
            int s = tid + i * 256;
            int row = s >> 3, p = s & 7, c = p ^ (row & 7);
            load16(Bt + (size_t)(bn * 128 + row) * K + kt + c * 8,
                   (char*)Bs + s * 16);
        }
        #pragma unroll
        for (int i = 0; i < 4; i++){    // convert + linear ds_write_b128
            int s = tid + i * 256;
            uint4 o;
            o.x = (uint_t)f2b(x[i].x) | ((uint_t)f2b(x[i].y) << 16);
            o.y = (uint_t)f2b(x[i].z) | ((uint_t)f2b(x[i].w) << 16);
            o.z = (uint_t)f2b(y[i].x) | ((uint_t)f2b(y[i].y) << 16);
            o.w = (uint_t)f2b(y[i].z) | ((uint_t)f2b(y[i].w) << 16);
            *(uint4*)(void*)((char*)As + s * 16) = o;
        }
        __syncthreads();
        #pragma unroll
        for (int ks = 0; ks < 2; ks++){
            const int c = (lane >> 4) + ks * 4;
            const int cx = c ^ (fr & 7);
            bf16x8 af[4], bf[4];
            #pragma unroll
            for (int t = 0; t < 4; t++)
                af[t] = *(const bf16x8*)(const void*)(As + (wm + t * 16 + fr) * 64 + cx * 8);
            #pragma unroll
            for (int t = 0; t < 4; t++)
                bf[t] = *(const bf16x8*)(const void*)(Bs + (wn + t * 16 + fr) * 64 + cx * 8);
            #pragma unroll
            for (int tm = 0; tm < 4; tm++)
                #pragma unroll
                for (int tn = 0; tn < 4; tn++)
                    acc[tm][tn] = __builtin_amdgcn_mfma_f32_16x16x32_bf16(
                                      af[tm], bf[tn], acc[tm][tn], 0, 0, 0);
        }
    }
    const int r0 = (lane >> 4) * 4, c0 = lane & 15;
    #pragma unroll
    for (int tm = 0; tm < 4; tm++){
        #pragma unroll
        for (int tn = 0; tn < 4; tn++){
            int rbase = bm * 128 + wm + tm * 16 + r0;
            int cidx  = bn * 128 + wn + tn * 16 + c0;
            #pragma unroll
            for (int reg = 0; reg < 4; reg++)
                C[(size_t)(rbase + reg) * 512 + cidx] = f2b(acc[tm][tn][reg]);
        }
    }
}

// ---------- aggregation ----------
__device__ __forceinline__ void acc8(float* a, uint4 y){
    a[0] += b2f((ushort_t)(y.x & 0xffff)); a[1] += b2f((ushort_t)(y.x >> 16));
    a[2] += b2f((ushort_t)(y.y & 0xffff)); a[3] += b2f((ushort_t)(y.y >> 16));
    a[4] += b2f((ushort_t)(y.z & 0xffff)); a[5] += b2f((ushort_t)(y.z >> 16));
    a[6] += b2f((ushort_t)(y.w & 0xffff)); a[7] += b2f((ushort_t)(y.w >> 16));
}
__device__ __forceinline__ void acc4(float* a, uint2 y){
    a[0] += b2f((ushort_t)(y.x & 0xffff)); a[1] += b2f((ushort_t)(y.x >> 16));
    a[2] += b2f((ushort_t)(y.y & 0xffff)); a[3] += b2f((ushort_t)(y.y >> 16));
}

// H[v] = relu((sum Y[nbr] + Y[v]) / (deg+1) + b), d=512, bf16 out.
// Dual-node waves (round-9, neutral-vs-best), 16B/lane loads preserved.
__global__ __launch_bounds__(256) void agg_relu_kernel(
        const ushort_t* __restrict__ Y, const int* __restrict__ offs,
        const int* __restrict__ nbr, const float* __restrict__ bias,
        ushort_t* __restrict__ H){
    const int lane = threadIdx.x & 63, wave = threadIdx.x >> 6;
    const int v0 = blockIdx.x * 8 + wave * 2, v1 = v0 + 1;
    const int off = lane * 8;
    float a0[8], a1[8];
    {   uint4 y = *(const uint4*)(const void*)(Y + (size_t)v0 * 512 + off);
        a0[0] = b2f((ushort_t)(y.x & 0xffff)); a0[1] = b2f((ushort_t)(y.x >> 16));
        a0[2] = b2f((ushort_t)(y.y & 0xffff)); a0[3] = b2f((ushort_t)(y.y >> 16));
        a0[4] = b2f((ushort_t)(y.z & 0xffff)); a0[5] = b2f((ushort_t)(y.z >> 16));
        a0[6] = b2f((ushort_t)(y.w & 0xffff)); a0[7] = b2f((ushort_t)(y.w >> 16)); }
    {   uint4 y = *(const uint4*)(const void*)(Y + (size_t)v1 * 512 + off);
        a1[0] = b2f((ushort_t)(y.x & 0xffff)); a1[1] = b2f((ushort_t)(y.x >> 16));
        a1[2] = b2f((ushort_t)(y.y & 0xffff)); a1[3] = b2f((ushort_t)(y.y >> 16));
        a1[4] = b2f((ushort_t)(y.z & 0xffff)); a1[5] = b2f((ushort_t)(y.z >> 16));
        a1[6] = b2f((ushort_t)(y.w & 0xffff)); a1[7] = b2f((ushort_t)(y.w >> 16)); }
    const int beg0 = offs[v0], end0 = offs[v0 + 1];
    const int beg1 = offs[v1], end1 = offs[v1 + 1];
    int i0 = beg0, i1 = beg1;
    while (i0 + 4 <= end0 && i1 + 4 <= end1){
        uint4 yy0[4], yy1[4];
        #pragma unroll
        for (int j = 0; j < 4; j++){
            int u = nbr[i0 + j];
            yy0[j] = *(const uint4*)(const void*)(Y + (size_t)u * 512 + off);
        }
        #pragma unroll
        for (int j = 0; j < 4; j++){
            int u = nbr[i1 + j];
            yy1[j] = *(const uint4*)(const void*)(Y + (size_t)u * 512 + off);
        }
        #pragma unroll
        for (int j = 0; j < 4; j++) acc8(a0, yy0[j]);
        #pragma unroll
        for (int j = 0; j < 4; j++) acc8(a1, yy1[j]);
        i0 += 4; i1 += 4;
    }
    for (; i0 + 4 <= end0; i0 += 4){
        uint4 yy[4];
        #pragma unroll
        for (int j = 0; j < 4; j++){
            int u = nbr[i0 + j];
            yy[j] = *(const uint4*)(const void*)(Y + (size_t)u * 512 + off);
        }
        #pragma unroll
        for (int j = 0; j < 4; j++) acc8(a0, yy[j]);
    }
    for (; i0 < end0; i0++){
        int u = nbr[i0];
        uint4 y = *(const uint4*)(const void*)(Y + (size_t)u * 512 + off);
        acc8(a0, y);
    }
    for (; i1 + 4 <= end1; i1 += 4){
        uint4 yy[4];
        #pragma unroll
        for (int j = 0; j < 4; j++){
            int u = nbr[i1 + j];
            yy[j] = *(const uint4*)(const void*)(Y + (size_t)u * 512 + off);
        }
        #pragma unroll
        for (int j = 0; j < 4; j++) acc8(a1, yy[j]);
    }
    for (; i1 < end1; i1++){
        int u = nbr[i1];
        uint4 y = *(const uint4*)(const void*)(Y + (size_t)u * 512 + off);
        acc8(a1, y);
    }
    float4 bb0 = ((const float4*)bias)[lane * 2];
    float4 bb1 = ((const float4*)bias)[lane * 2 + 1];
    {
        const float inv = 1.0f / (float)(end0 - beg0 + 1);
        float r[8];
        r[0] = a0[0]*inv + bb0.x; r[1] = a0[1]*inv + bb0.y;
        r[2] = a0[2]*inv + bb0.z; r[3] = a0[3]*inv + bb0.w;
        r[4] = a0[4]*inv + bb1.x; r[5] = a0[5]*inv + bb1.y;
        r[6] = a0[6]*inv + bb1.z; r[7] = a0[7]*inv + bb1.w;
        #pragma unroll
        for (int j = 0; j < 8; j++) r[j] = r[j] > 0.f ? r[j] : 0.f;
        uint4 o;
        o.x = (uint_t)f2b(r[0]) | ((uint_t)f2b(r[1]) << 16);
        o.y = (uint_t)f2b(r[2]) | ((uint_t)f2b(r[3]) << 16);
        o.z = (uint_t)f2b(r[4]) | ((uint_t)f2b(r[5]) << 16);
        o.w = (uint_t)f2b(r[6]) | ((uint_t)f2b(r[7]) << 16);
        *(uint4*)(void*)(H + (size_t)v0 * 512 + off) = o;
    }
    {
        const float inv = 1.0f / (float)(end1 - beg1 + 1);
        float r[8];
        r[0] = a1[0]*inv + bb0.x; r[1] = a1[1]*inv + bb0.y;
        r[2] = a1[2]*inv + bb0.z; r[3] = a1[3]*inv + bb0.w;
        r[4] = a1[4]*inv + bb1.x; r[5] = a1[5]*inv + bb1.y;
        r[6] = a1[6]*inv + bb1.z; r[7] = a1[7]*inv + bb1.w;
        #pragma unroll
        for (int j = 0; j < 8; j++) r[j] = r[j] > 0.f ? r[j] : 0.f;
        uint4 o;
        o.x = (uint_t)f2b(r[0]) | ((uint_t)f2b(r[1]) << 16);
        o.y = (uint_t)f2b(r[2]) | ((uint_t)f2b(r[3]) << 16);
        o.z = (uint_t)f2b(r[4]) | ((uint_t)f2b(r[5]) << 16);
        o.w = (uint_t)f2b(r[6]) | ((uint_t)f2b(r[7]) << 16);
        *(uint4*)(void*)(H + (size_t)v1 * 512 + off) = o;
    }
}

// final layer: d=256, fp32 out, no relu. wave per node, lane covers 4 elems
__global__ __launch_bounds__(256) void agg_out_kernel(
        const ushort_t* __restrict__ Y, const int* __restrict__ offs,
        const int* __restrict__ nbr, const float* __restrict__ bias,
        float* __restrict__ out){
    const int lane = threadIdx.x & 63, wave = threadIdx.x >> 6;
    const int v = blockIdx.x * 4 + wave;
    const int off = lane * 4;
    float a[4];
    {   uint2 y = *(const uint2*)(const void*)(Y + (size_t)v * 256 + off);
        a[0] = b2f((ushort_t)(y.x & 0xffff)); a[1] = b2f((ushort_t)(y.x >> 16));
        a[2] = b2f((ushort_t)(y.y & 0xffff)); a[3] = b2f((ushort_t)(y.y >> 16)); }
    const int beg = offs[v], end = offs[v + 1];
    int i = beg;
    for (; i + 8 <= end; i += 8){
        uint2 yy[8];
        #pragma unroll
        for (int j = 0; j < 8; j++){
            int u = nbr[i + j];
            yy[j] = *(const uint2*)(const void*)(Y + (size_t)u * 256 + off);
        }
        #pragma unroll
        for (int j = 0; j < 8; j++) acc4(a, yy[j]);
    }
    for (; i + 4 <= end; i += 4){
        uint2 yy[4];
        #pragma unroll
        for (int j = 0; j < 4; j++){
            int u = nbr[i + j];
            yy[j] = *(const uint2*)(const void*)(Y + (size_t)u * 256 + off);
        }
        #pragma unroll
        for (int j = 0; j < 4; j++) acc4(a, yy[j]);
    }
    for (; i < end; i++){
        int u = nbr[i];
        uint2 y = *(const uint2*)(const void*)(Y + (size_t)u * 256 + off);
        acc4(a, y);
    }
    const float inv = 1.0f / (float)(end - beg + 1);
    float4 bb = ((const float4*)bias)[lane];
    float4 r;
    r.x = a[0]*inv + bb.x; r.y = a[1]*inv + bb.y;
    r.z = a[2]*inv + bb.z; r.w = a[3]*inv + bb.w;
    ((float4*)out)[v * 64 + lane] = r;
}

extern "C" void kernel_launch(void* const* d_in, const int* in_sizes, int n_in,
                              void* d_out, int out_size, void* d_ws, size_t ws_size,
                              hipStream_t stream) {
    const float* feats = (const float*)d_in[0];
    const int*   src   = (const int*)  d_in[1];
    const int*   dst   = (const int*)  d_in[2];
    const float* W0    = (const float*)d_in[3];
    const float* b0    = (const float*)d_in[4];
    const float* W1    = (const float*)d_in[5];
    const float* b1    = (const float*)d_in[6];
    const float* W2    = (const float*)d_in[7];
    const float* b2    = (const float*)d_in[8];
    float* out = (float*)d_out;

    char* w = (char*)d_ws;
    ushort_t* Abuf = (ushort_t*)w;  w += (size_t)MPAD * 512 * 2;   // 51.25 MB (H buffer)
    ushort_t* Ybuf = (ushort_t*)w;  w += (size_t)MPAD * 512 * 2;   // 51.25 MB
    ushort_t* W0t  = (ushort_t*)w;  w += 512 * 512 * 2;
    ushort_t* W1t  = (ushort_t*)w;  w += 512 * 512 * 2;
    ushort_t* W2t  = (ushort_t*)w;  w += 256 * 512 * 2;
    int* deg    = (int*)w;          w += 50048 * 4;
    int* offs   = (int*)w;          w += 50056 * 4;
    int* cursor = (int*)w;          w += 50048 * 4;
    int* nbr    = (int*)w;          w += (size_t)N_EDGES * 4;
    int* bsum   = (int*)w;          w += 64 * 4;

    // L1: weight transposes + deg/cursor zero (fused; round-10 harmless)
    pre_kernel<<<836, 256, 0, stream>>>(W0, W1, W2, W0t, W1t, W2t, deg, cursor);
    // L2: layer-0 GEMM + degree histogram (fused; round-10 harmless)
    gemm128_a32h<<<G_GEMM + H_BLKS, 256, 0, stream>>>(feats, W0t, Ybuf, dst, deg, 512);
    // L3/L4: scan (multi-block; round-10's single-block scan was 87 us)
    blk_scan_kernel<<<SCAN_B, 1024, 0, stream>>>(deg, offs, bsum, N_NODES);
    add_off2_kernel<<<SCAN_B, 1024, 0, stream>>>(offs, bsum, N_NODES);
    // L5: CSR fill
    fill_kernel<<<H_BLKS, 256, 0, stream>>>(src, dst, offs, cursor, nbr, N_EDGES);
    // L6: layer-0 aggregation
    agg_relu_kernel<<<N_NODES / 8, 256, 0, stream>>>(Ybuf, offs, nbr, b0, Abuf);
    // L7/L8: layer 1
    gemm128_bt<<<(MPAD / 128) * 4, 256, 0, stream>>>(Abuf, W1t, Ybuf, 4, 512, 512);
    agg_relu_kernel<<<N_NODES / 8, 256, 0, stream>>>(Ybuf, offs, nbr, b1, Abuf);
    // L9/L10: layer 2 (no relu, fp32 out)
    gemm128_bt<<<(MPAD / 128) * 2, 256, 0, stream>>>(Abuf, W2t, Ybuf, 2, 256, 512);
    agg_out_kernel<<<N_NODES / 4, 256, 0, stream>>>(Ybuf, offs, nbr, b2, out);
}